// Round 3
// baseline (431.431 us; speedup 1.0000x reference)
//
#include <hip/hip_runtime.h>
#include <hip/hip_bf16.h>

// GatedReadout: out[64][512] = concat(segment_mean(gated), segment_max(gated))
// gated = sigmoid(nodes@Wg+bg) * tanh(nodes@Wf+bf) * mask
// nodes (262144,256) f32, indicator sorted int in [0,64), weights (256,256) f32.
//
// R3: barrier-free K-loop + 2 blocks/CU (__launch_bounds__(512,4)) + explicit
// B double-buffer prefetch + cvt_pk bf16 staging. B pre-swizzled into MFMA
// fragment order by gr_init; loaded straight from L2 into registers.

#define N_NODES 262144
#define BM 64
#define NBLK (N_NODES / BM)   // 4096

typedef short bf16x8 __attribute__((ext_vector_type(8)));
typedef float f32x4 __attribute__((ext_vector_type(4)));

// ws layout (bytes)
#define BT_OFF      0          // bf16 fragment-ordered B: 32 tiles x 8 ks x 64 lanes x 16B = 262144 B
#define SEG_SUM_OFF 262144     // f32 [64][256] = 65536 B
#define SEG_MAX_OFF 327680     // f32 [64][256] = 65536 B
#define SEG_CNT_OFF 393216     // f32 [64]      = 256 B

__device__ __forceinline__ unsigned short f2bf(float x) {
    unsigned u = __float_as_uint(x);
    u += 0x7FFFu + ((u >> 16) & 1u);   // round-to-nearest-even
    return (unsigned short)(u >> 16);
}

__device__ __forceinline__ void atomicMaxF(float* addr, float v) {
    // int-max for v>=0, uint-min for v<0; init must be -inf (0xFF800000)
    if (v >= 0.0f) atomicMax((int*)addr, __float_as_int(v));
    else           atomicMin((unsigned int*)addr, __float_as_uint(v));
}

__device__ __forceinline__ float fast_sigmoid(float x) {
    return __builtin_amdgcn_rcpf(1.0f + __builtin_amdgcn_exp2f(-1.4426950408889634f * x));
}
__device__ __forceinline__ float fast_tanh(float x) {
    return 1.0f - 2.0f * __builtin_amdgcn_rcpf(1.0f + __builtin_amdgcn_exp2f(2.8853900817779268f * x));
}

// ---- kernel 0: weight transpose+convert into fragment order + accumulator init
// Fragment granule (tile, ks, lane) holds Bt[col = tile*16 + (lane&15)]
//                                          [k = ks*32 + (lane>>4)*8 .. +8]  (8 bf16 = 16B)
__global__ void gr_init(const float* __restrict__ Wg, const float* __restrict__ Wf,
                        unsigned short* __restrict__ Btf, float* __restrict__ seg_sum,
                        float* __restrict__ seg_max, float* __restrict__ seg_cnt) {
    int b = blockIdx.x;
    int t = threadIdx.x;
    if (b >= 32) {
        int tid = (b - 32) * 256 + t;        // 1024 threads
        for (int i = tid; i < 16384; i += 1024) {
            seg_sum[i] = 0.0f;
            seg_max[i] = __uint_as_float(0xFF800000u);
        }
        if (tid < 64) seg_cnt[tid] = 0.0f;
        return;
    }
    __shared__ float lds[64][68];            // +4 pad
    const int kt  = b >> 3;                  // 0..3  -> k0 = kt*64
    const int ct0 = (b & 7) * 64;            // combined col 0..448
    const float* W = (ct0 < 256) ? Wg : Wf;
    const int cbase = (ct0 < 256) ? ct0 : ct0 - 256;
    #pragma unroll
    for (int p = 0; p < 4; ++p) {
        int kk = (t >> 4) + p * 16;
        int cc = (t & 15) * 4;
        float4 v = *(const float4*)(W + (kt * 64 + kk) * 256 + cbase + cc);
        lds[kk][cc] = v.x; lds[kk][cc + 1] = v.y; lds[kk][cc + 2] = v.z; lds[kk][cc + 3] = v.w;
    }
    __syncthreads();
    #pragma unroll
    for (int p = 0; p < 2; ++p) {
        int g = t + p * 256;                 // 512 granules/block
        int lane = g & 63, ksg = (g >> 6) & 1, ct = g >> 7;  // ct 0..3
        int cc = ct * 16 + (lane & 15);
        int kk = ksg * 32 + (lane >> 4) * 8;
        union { bf16x8 v; unsigned short u[8]; } w;
        #pragma unroll
        for (int j = 0; j < 8; ++j) w.u[j] = f2bf(lds[kk + j][cc]);
        int gct = (ct0 >> 4) + ct;           // global colTile 0..31 (0-15 gate, 16-31 feat)
        int ks  = kt * 2 + ksg;              // 0..7
        *reinterpret_cast<bf16x8*>(Btf + (((gct * 8 + ks) * 64 + lane) << 3)) = w.v;
    }
}

// ---- kernel 1: fused GEMM(x2) + gating + segment reduce, barrier-free K-loop
__global__ __launch_bounds__(512, 4) void gr_main(
    const float* __restrict__ nodes, const int* __restrict__ indicator,
    const float* __restrict__ mask, const float* __restrict__ bg,
    const float* __restrict__ bfb, const unsigned short* __restrict__ Btf,
    float* __restrict__ seg_sum, float* __restrict__ seg_max, float* __restrict__ seg_cnt)
{
    // A rows padded to 264 shorts (528 B): staging conflict-free, frag reads 2-way (free)
    __shared__ unsigned short sA[64 * 264];  // 33792 B
    __shared__ float sMask[64];
    __shared__ int sSeg[64];

    const int t = threadIdx.x;
    const long r0 = (long)blockIdx.x * BM;

    // ---- stage A: 64 rows x 256 k, fp32 -> bf16 (the only barrier in the kernel)
    #pragma unroll
    for (int i = 0; i < 4; ++i) {
        int c = t + i * 512;                 // granule 0..2047 (8 elems)
        int row = c >> 5, g = c & 31;
        const float* src = nodes + (r0 + row) * 256 + g * 8;
        float4 f0 = *(const float4*)(src);
        float4 f1 = *(const float4*)(src + 4);
        union { bf16x8 v; __hip_bfloat162 h[4]; } w;
        w.h[0] = __float22bfloat162_rn(make_float2(f0.x, f0.y));
        w.h[1] = __float22bfloat162_rn(make_float2(f0.z, f0.w));
        w.h[2] = __float22bfloat162_rn(make_float2(f1.x, f1.y));
        w.h[3] = __float22bfloat162_rn(make_float2(f1.z, f1.w));
        *reinterpret_cast<bf16x8*>(&sA[row * 264 + g * 8]) = w.v;
    }
    if (t < 64) { sMask[t] = mask[r0 + t]; sSeg[t] = indicator[r0 + t]; }

    const int lane = t & 63, wc = t >> 6;    // wave wc owns e-range [wc*32, wc*32+32)
    const int l15 = lane & 15, l4 = lane >> 4;

    // preload bias while A-stage is in flight
    float bgv0 = bg[wc * 32 + l15],  bgv1 = bg[wc * 32 + 16 + l15];
    float bfv0 = bfb[wc * 32 + l15], bfv1 = bfb[wc * 32 + 16 + l15];

    __syncthreads();

    f32x4 acc[4][4];                          // [row-tile m][n: 0,1 gate / 2,3 feat]
    #pragma unroll
    for (int m = 0; m < 4; ++m)
        #pragma unroll
        for (int n = 0; n < 4; ++n) acc[m][n] = (f32x4){0.f, 0.f, 0.f, 0.f};

    const bf16x8* __restrict__ B8 = (const bf16x8*)Btf;  // granule-indexed
    // tiles owned by this wave: gate wc*2, wc*2+1; feat 16+wc*2, 17+wc*2
    const int tb0 = (wc * 2) * 8 * 64 + lane;

    bf16x8 bcur[4], bnxt[4];
    bcur[0] = B8[tb0];
    bcur[1] = B8[tb0 + 8 * 64];
    bcur[2] = B8[tb0 + 16 * 8 * 64];
    bcur[3] = B8[tb0 + 17 * 8 * 64];

    #pragma unroll
    for (int ks = 0; ks < 8; ++ks) {
        if (ks < 7) {
            int o = (ks + 1) * 64;
            bnxt[0] = B8[tb0 + o];
            bnxt[1] = B8[tb0 + 8 * 64 + o];
            bnxt[2] = B8[tb0 + 16 * 8 * 64 + o];
            bnxt[3] = B8[tb0 + 17 * 8 * 64 + o];
        }
        bf16x8 a[4];
        #pragma unroll
        for (int m = 0; m < 4; ++m)
            a[m] = *reinterpret_cast<const bf16x8*>(&sA[(m * 16 + l15) * 264 + ks * 32 + l4 * 8]);
        #pragma unroll
        for (int m = 0; m < 4; ++m)
            #pragma unroll
            for (int n = 0; n < 4; ++n)
                acc[m][n] = __builtin_amdgcn_mfma_f32_16x16x32_bf16(a[m], bcur[n], acc[m][n], 0, 0, 0);
        #pragma unroll
        for (int n = 0; n < 4; ++n) bcur[n] = bnxt[n];
    }

    // ---- epilogue: gate*feat*mask
    // C frag: col = lane&15, row = m*16 + (lane>>4)*4 + i
    float4 mk[4];
    #pragma unroll
    for (int m = 0; m < 4; ++m) mk[m] = *reinterpret_cast<const float4*>(&sMask[m * 16 + l4 * 4]);

    float gated[4][2][4];
    #pragma unroll
    for (int m = 0; m < 4; ++m)
        #pragma unroll
        for (int i = 0; i < 4; ++i) {
            float mv = (i == 0) ? mk[m].x : (i == 1) ? mk[m].y : (i == 2) ? mk[m].z : mk[m].w;
            float g0 = acc[m][0][i] + bgv0;
            float h0 = acc[m][2][i] + bfv0;
            gated[m][0][i] = fast_sigmoid(g0) * fast_tanh(h0) * mv;
            float g1 = acc[m][1][i] + bgv1;
            float h1 = acc[m][3][i] + bfv1;
            gated[m][1][i] = fast_sigmoid(g1) * fast_tanh(h1) * mv;
        }

    // ---- segment reduce
    if (sSeg[0] == sSeg[63]) {
        int sg = sSeg[0];
        #pragma unroll
        for (int np = 0; np < 2; ++np) {
            float s = 0.f, mx = -3.4e38f;
            #pragma unroll
            for (int m = 0; m < 4; ++m)
                #pragma unroll
                for (int i = 0; i < 4; ++i) {
                    s += gated[m][np][i];
                    mx = fmaxf(mx, gated[m][np][i]);
                }
            s += __shfl_xor(s, 16); s += __shfl_xor(s, 32);
            mx = fmaxf(mx, __shfl_xor(mx, 16)); mx = fmaxf(mx, __shfl_xor(mx, 32));
            if (l4 == 0) {
                int e = wc * 32 + np * 16 + l15;
                atomicAdd(&seg_sum[sg * 256 + e], s);
                atomicMaxF(&seg_max[sg * 256 + e], mx);
            }
        }
    } else {
        // boundary block (~63 of 4096): per-16-row-tile fast/slow
        #pragma unroll
        for (int m = 0; m < 4; ++m) {
            int sgA = sSeg[m * 16], sgB = sSeg[m * 16 + 15];
            if (sgA == sgB) {
                #pragma unroll
                for (int np = 0; np < 2; ++np) {
                    float s = 0.f, mx = -3.4e38f;
                    #pragma unroll
                    for (int i = 0; i < 4; ++i) {
                        s += gated[m][np][i];
                        mx = fmaxf(mx, gated[m][np][i]);
                    }
                    s += __shfl_xor(s, 16); s += __shfl_xor(s, 32);
                    mx = fmaxf(mx, __shfl_xor(mx, 16)); mx = fmaxf(mx, __shfl_xor(mx, 32));
                    if (l4 == 0) {
                        int e = wc * 32 + np * 16 + l15;
                        atomicAdd(&seg_sum[sgA * 256 + e], s);
                        atomicMaxF(&seg_max[sgA * 256 + e], mx);
                    }
                }
            } else {
                #pragma unroll
                for (int np = 0; np < 2; ++np) {
                    int e = wc * 32 + np * 16 + l15;
                    #pragma unroll
                    for (int i = 0; i < 4; ++i) {
                        int row = m * 16 + l4 * 4 + i;
                        int sg = sSeg[row];
                        atomicAdd(&seg_sum[sg * 256 + e], gated[m][np][i]);
                        atomicMaxF(&seg_max[sg * 256 + e], gated[m][np][i]);
                    }
                }
            }
        }
    }

    // seg_cnt: wave 0 reduces the block's 64 mask values
    if (wc == 0) {
        float mv = sMask[lane];
        if (sSeg[0] == sSeg[63]) {
            float tot = mv;
            #pragma unroll
            for (int off = 1; off < 64; off <<= 1) tot += __shfl_xor(tot, off);
            if (lane == 0) atomicAdd(&seg_cnt[sSeg[0]], tot);
        } else {
            atomicAdd(&seg_cnt[sSeg[lane]], mv);
        }
    }
}

// ---- kernel 2: finalize  out[s][0:256]=mean, out[s][256:512]=max
__global__ void gr_final(const float* __restrict__ seg_sum, const float* __restrict__ seg_max,
                         const float* __restrict__ seg_cnt, float* __restrict__ out) {
    int tid = blockIdx.x * 256 + threadIdx.x;   // 32768
    int s = tid >> 9, j = tid & 511;
    float r;
    if (j < 256) r = seg_sum[s * 256 + j] / fmaxf(seg_cnt[s], 1e-6f);
    else         r = seg_max[s * 256 + (j - 256)];
    out[tid] = r;
}

extern "C" void kernel_launch(void* const* d_in, const int* in_sizes, int n_in,
                              void* d_out, int out_size, void* d_ws, size_t ws_size,
                              hipStream_t stream) {
    const float* nodes     = (const float*)d_in[0];
    const int*   indicator = (const int*)d_in[1];
    const float* mask      = (const float*)d_in[2];
    const float* Wg        = (const float*)d_in[3];
    const float* bg        = (const float*)d_in[4];
    const float* Wf        = (const float*)d_in[5];
    const float* bf        = (const float*)d_in[6];
    float* out = (float*)d_out;

    unsigned short* Btf = (unsigned short*)((char*)d_ws + BT_OFF);
    float* seg_sum = (float*)((char*)d_ws + SEG_SUM_OFF);
    float* seg_max = (float*)((char*)d_ws + SEG_MAX_OFF);
    float* seg_cnt = (float*)((char*)d_ws + SEG_CNT_OFF);

    gr_init<<<48, 256, 0, stream>>>(Wg, Wf, Btf, seg_sum, seg_max, seg_cnt);
    gr_main<<<NBLK, 512, 0, stream>>>(nodes, indicator, mask, bg, bf, Btf,
                                      seg_sum, seg_max, seg_cnt);
    gr_final<<<128, 256, 0, stream>>>(seg_sum, seg_max, seg_cnt, out);
}